// Round 5
// baseline (171.232 us; speedup 1.0000x reference)
//
#include <hip/hip_runtime.h>
#include <hip/hip_fp16.h>
#include <math.h>

#define N_IN   512
#define N_OUT  256
#define NCOEF  257
#define BATCH  1024
#define LN_EPS 1e-5f
#define G0F (-1.0f - 3.0f * (2.0f / 254.0f))

#define ROWQ 18                 // dwords per q-row: 16 data + 2 pad (bank spread)
#define NQ   129                // q-rows: g-pairs (0,1)..(256,pad)
#define SLABW (NQ * ROWQ)

// physical dword of logical (q-row, o-col): slot = (oo>>1) ^ (q&7)
#define SLOT(q_, oo_) ((q_) * ROWQ + (((((oo_) >> 1) ^ ((q_) & 7))) << 1) + ((oo_) & 1))

static __device__ __forceinline__ unsigned pk_bf16x2(float a, float b) {
    unsigned ua = ((__float_as_uint(a) + 0x8000u) >> 16) & 0xffffu;
    unsigned ub = (__float_as_uint(b) + 0x8000u) & 0xffff0000u;
    return ua | ub;
}

static __device__ __forceinline__ float dot2bf(unsigned w, unsigned s, float c) {
    float d;
    asm("v_dot2_f32_bf16 %0, %1, %2, %3" : "=v"(d) : "v"(w), "v"(s), "v"(c));
    return d;
}

// 6-wide even-aligned spline window: w'[j] for g = pe+j, pe = clamp(pb)&~1.
// uint4: x=(w'0,w'1) y=(w'2,w'3) z=(w'4,w'5) bf16-pairs; w = pe | f16(tanh)<<16
static __device__ __forceinline__ uint4 spline_pack(float xv) {
    const float e2 = __expf(2.f * xv);
    const float tx = 1.f - 2.f / (e2 + 1.f);        // tanh(xv)
    const float u  = (xv - G0F) * 127.f;
    const bool has = (u >= 0.f) && (u < 260.f);
    const float uf = has ? u : 0.f;
    int m = (int)uf;
    if (m > 259) m = 259;
    const float tt = uf - (float)m;
    const float t2 = tt * tt, t3 = t2 * tt;
    const float omt = 1.f - tt;
    float a0 = omt * omt * omt * (1.f / 6.f);
    float a1 = (3.f * t3 - 6.f * t2 + 4.f) * (1.f / 6.f);
    float a2 = (-3.f * t3 + 3.f * t2 + 3.f * tt + 1.f) * (1.f / 6.f);
    float a3 = t3 * (1.f / 6.f);
    if (!has) { a0 = a1 = a2 = a3 = 0.f; }
    const int pb  = m - 3;
    const int pbc = pb < 0 ? 0 : (pb > 253 ? 253 : pb);
    const int d   = pbc - pb;                       // [-3,3]
    if (d >= 1)  { a0 = a1; a1 = a2; a2 = a3; a3 = 0.f; }
    if (d >= 2)  { a0 = a1; a1 = a2; a2 = a3; a3 = 0.f; }
    if (d >= 3)  { a0 = a1; a1 = a2; a2 = a3; a3 = 0.f; }
    if (d <= -1) { a3 = a2; a2 = a1; a1 = a0; a0 = 0.f; }
    if (d <= -2) { a3 = a2; a2 = a1; a1 = a0; a0 = 0.f; }
    if (d <= -3) { a3 = a2; a2 = a1; a1 = a0; a0 = 0.f; }
    uint4 r;
    if (pbc & 1) {        // window (0,a0,a1,a2,a3,0)
        r.x = pk_bf16x2(0.f, a0);
        r.y = pk_bf16x2(a1, a2);
        r.z = pk_bf16x2(a3, 0.f);
    } else {              // window (a0,a1,a2,a3,0,0)
        r.x = pk_bf16x2(a0, a1);
        r.y = pk_bf16x2(a2, a3);
        r.z = 0u;
    }
    r.w = (unsigned)(pbc & ~1) |
          ((unsigned)__half_as_ushort(__float2half(tx)) << 16);
    return r;
}

__global__ void kan_zero(float* __restrict__ y) {
    y[(size_t)blockIdx.x * 256 + threadIdx.x] = 0.f;
}

__global__ __launch_bounds__(512, 8) void kan_main(
    const float* __restrict__ x, const float* __restrict__ W,
    const float* __restrict__ sw, float* __restrict__ y)
{
    const int bid = blockIdx.x;
    const int bc = bid & 1;             // fastest: b-split sharers co-resident
    const int oc = (bid >> 1) & 15;
    const int ig = bid >> 5;            // [0,32)
    const int o0 = oc * 16, i0 = ig * 16, b0 = bc * 512;
    const int t = threadIdx.x;

    __shared__ __align__(16) unsigned slab[2][SLABW];   // 18.6 KB
    __shared__ __align__(16) uint4 wpk[2][512];         // 16 KB
    __shared__ float Wl[2][16];

    // compute mapping: b = wv*64 + bp*16 + bl; o = o0 + og*4 + j
    const int wv = t >> 6, bl = (t >> 2) & 15, og = t & 3;
    const int og2 = og << 1;
    // staging mapping: o-row soo, g-chunk gc
    const int soo = t >> 5;             // [0,16)
    const int gc  = t & 31;             // [0,32)

    const float* swrow = sw + ((size_t)(o0 + soo) * N_IN + i0) * NCOEF;
    const float* xp    = x + (size_t)(b0 + t) * N_IN + i0;
    const float* wgp   = W + (size_t)(o0 + (t & 15)) * N_IN + i0;

    float4 sA, sB;
    float sT = 0.f, Wc = 0.f, xc, xn;

#define GLOAD(ii) do {                                            \
        const float* _r = swrow + (size_t)(ii) * NCOEF;           \
        sA = *(const float4*)&_r[gc * 4];                         \
        sB = *(const float4*)&_r[gc * 4 + 128];                   \
        if (gc == 0) sT = _r[256];                                \
    } while (0)

#define STAGE(SL) do {                                            \
        const int qa = gc * 2, qb = qa + 64;                      \
        (SL)[SLOT(qa,     soo)] = pk_bf16x2(sA.x, sA.y);          \
        (SL)[SLOT(qa + 1, soo)] = pk_bf16x2(sA.z, sA.w);          \
        (SL)[SLOT(qb,     soo)] = pk_bf16x2(sB.x, sB.y);          \
        (SL)[SLOT(qb + 1, soo)] = pk_bf16x2(sB.z, sB.w);          \
        if (gc == 0) (SL)[128 * ROWQ + soo] = pk_bf16x2(sT, 0.f); \
    } while (0)

    // ---- prologue: stage i=0 into buf0, prefetch i=1
    xc = xp[0];
    GLOAD(0);
    if (t < 16) Wc = wgp[0];
    unsigned* slC = slab[0]; unsigned* slN = slab[1];
    uint4*    wkC = wpk[0];  uint4*    wkN = wpk[1];
    float*    WlC = Wl[0];   float*    WlN = Wl[1];
    STAGE(slC);
    wkC[t] = spline_pack(xc);
    if (t < 16) WlC[t] = Wc;
    xn = xp[1];
    GLOAD(1);
    if (t < 16) Wc = wgp[1];

    float4 acc[4];
#pragma unroll
    for (int bp = 0; bp < 4; ++bp) acc[bp] = make_float4(0.f, 0.f, 0.f, 0.f);

    __syncthreads();

    for (int n = 0; n < 16; ++n) {
        // ---- compute i=n from slC / wkC / WlC
        const float4 Wv = *(const float4*)&WlC[og << 2];
#pragma unroll
        for (int bp = 0; bp < 4; ++bp) {
            const uint4 u = wkC[wv * 64 + (bp << 4) + bl];   // b128 broadcast x4
            const int pe = (int)(u.w & 0xffffu);
            const float tx =
                __half2float(__ushort_as_half((unsigned short)(u.w >> 16)));
            const int q0 = pe >> 1;
            float4 a = acc[bp];
            a.x = fmaf(tx, Wv.x, a.x);
            a.y = fmaf(tx, Wv.y, a.y);
            a.z = fmaf(tx, Wv.z, a.z);
            a.w = fmaf(tx, Wv.w, a.w);
#pragma unroll
            for (int j = 0; j < 3; ++j) {
                const int q = q0 + j;
                const int s = og2 ^ (q & 7);
                const int rb = q * ROWQ;
                const uint2 A = *(const uint2*)&slC[rb + (s << 1)];
                const uint2 B = *(const uint2*)&slC[rb + ((s ^ 1) << 1)];
                const unsigned wj = (j == 0) ? u.x : (j == 1) ? u.y : u.z;
                a.x = dot2bf(wj, A.x, a.x);
                a.y = dot2bf(wj, A.y, a.y);
                a.z = dot2bf(wj, B.x, a.z);
                a.w = dot2bf(wj, B.y, a.w);
            }
            acc[bp] = a;
        }

        // ---- stage i=n+1 into the other buffer; prefetch i=n+2
        if (n + 1 < 16) {
            STAGE(slN);
            wkN[t] = spline_pack(xn);
            if (t < 16) WlN[t] = Wc;
            if (n + 2 < 16) {
                xn = xp[n + 2];
                GLOAD(n + 2);
                if (t < 16) Wc = wgp[n + 2];
            }
        }
        __syncthreads();
        { unsigned* z = slC; slC = slN; slN = z; }
        { uint4*    z = wkC; wkC = wkN; wkN = z; }
        { float*    z = WlC; WlC = WlN; WlN = z; }
    }

    // ---- accumulate into y via device atomics (32 i-groups sum here)
    float* yb = y + (size_t)b0 * N_OUT + o0 + (og << 2);
#pragma unroll
    for (int bp = 0; bp < 4; ++bp) {
        const int lb = wv * 64 + (bp << 4) + bl;
        float* p = yb + (size_t)lb * N_OUT;
        atomicAdd(p + 0, acc[bp].x);
        atomicAdd(p + 1, acc[bp].y);
        atomicAdd(p + 2, acc[bp].z);
        atomicAdd(p + 3, acc[bp].w);
    }
#undef GLOAD
#undef STAGE
}

__global__ __launch_bounds__(256) void kan_ln(
    const float* __restrict__ y, const float* __restrict__ prelu_a,
    float* __restrict__ out)
{
    const int b = blockIdx.x;
    const int t = threadIdx.x;

    const float sv = y[(size_t)b * N_OUT + t];

    float v1 = sv, v2 = sv * sv;
#pragma unroll
    for (int d = 1; d < 64; d <<= 1) {
        v1 += __shfl_xor(v1, d);
        v2 += __shfl_xor(v2, d);
    }
    __shared__ float r1[4], r2[4];
    if ((t & 63) == 0) { r1[t >> 6] = v1; r2[t >> 6] = v2; }
    __syncthreads();
    const float tot1 = r1[0] + r1[1] + r1[2] + r1[3];
    const float tot2 = r2[0] + r2[1] + r2[2] + r2[3];

    const float mu  = tot1 * (1.f / N_OUT);
    const float var = tot2 * (1.f / N_OUT) - mu * mu;
    const float inv = rsqrtf(var + LN_EPS);
    const float yn  = (sv - mu) * inv;
    const float a   = prelu_a[0];
    out[(size_t)b * N_OUT + t] = (yn >= 0.f) ? yn : a * yn;
}

extern "C" void kernel_launch(void* const* d_in, const int* in_sizes, int n_in,
                              void* d_out, int out_size, void* d_ws, size_t ws_size,
                              hipStream_t stream)
{
    const float* x  = (const float*)d_in[0];
    const float* W  = (const float*)d_in[1];
    const float* sw = (const float*)d_in[2];
    const float* pa = (const float*)d_in[3];
    float* out = (float*)d_out;
    float* yws = (float*)d_ws;          // BATCH * N_OUT floats = 1 MB

    kan_zero<<<dim3(1024), 256, 0, stream>>>(yws);
    kan_main<<<dim3(1024), 512, 0, stream>>>(x, W, sw, yws);
    kan_ln  <<<dim3(1024), 256, 0, stream>>>(yws, pa, out);
}

// Round 6
// 165.694 us; speedup vs baseline: 1.0334x; 1.0334x over previous
//
#include <hip/hip_runtime.h>
#include <hip/hip_fp16.h>
#include <math.h>

#define N_IN   512
#define N_OUT  256
#define NCOEF  257
#define BATCH  1024
#define LN_EPS 1e-5f
#define G0F (-1.0f - 3.0f * (2.0f / 254.0f))

#define ROWQ 18                 // dwords per q-row: 16 data + 2 pad (bank spread)
#define NQ   129                // q-rows: g-pairs (0,1)..(256,pad)
#define SLABW (NQ * ROWQ)

// physical dword of logical (q-row, o-col): slot = (oo>>1) ^ (q&7)
#define SLOT(q_, oo_) ((q_) * ROWQ + (((((oo_) >> 1) ^ ((q_) & 7))) << 1) + ((oo_) & 1))

static __device__ __forceinline__ unsigned pk_bf16x2(float a, float b) {
    unsigned ua = ((__float_as_uint(a) + 0x8000u) >> 16) & 0xffffu;
    unsigned ub = (__float_as_uint(b) + 0x8000u) & 0xffff0000u;
    return ua | ub;
}

static __device__ __forceinline__ float dot2bf(unsigned w, unsigned s, float c) {
    float d;
    asm("v_dot2_f32_bf16 %0, %1, %2, %3" : "=v"(d) : "v"(w), "v"(s), "v"(c));
    return d;
}

// 6-wide even-aligned spline window: w'[j] for g = pe+j, pe = clamp(pb)&~1.
// uint4: x=(w'0,w'1) y=(w'2,w'3) z=(w'4,w'5) bf16-pairs; w = pe | f16(tanh)<<16
static __device__ __forceinline__ uint4 spline_pack(float xv) {
    const float e2 = __expf(2.f * xv);
    const float tx = 1.f - 2.f / (e2 + 1.f);        // tanh(xv)
    const float u  = (xv - G0F) * 127.f;
    const bool has = (u >= 0.f) && (u < 260.f);
    const float uf = has ? u : 0.f;
    int m = (int)uf;
    if (m > 259) m = 259;
    const float tt = uf - (float)m;
    const float t2 = tt * tt, t3 = t2 * tt;
    const float omt = 1.f - tt;
    float a0 = omt * omt * omt * (1.f / 6.f);
    float a1 = (3.f * t3 - 6.f * t2 + 4.f) * (1.f / 6.f);
    float a2 = (-3.f * t3 + 3.f * t2 + 3.f * tt + 1.f) * (1.f / 6.f);
    float a3 = t3 * (1.f / 6.f);
    if (!has) { a0 = a1 = a2 = a3 = 0.f; }
    const int pb  = m - 3;
    const int pbc = pb < 0 ? 0 : (pb > 253 ? 253 : pb);
    const int d   = pbc - pb;                       // [-3,3]
    if (d >= 1)  { a0 = a1; a1 = a2; a2 = a3; a3 = 0.f; }
    if (d >= 2)  { a0 = a1; a1 = a2; a2 = a3; a3 = 0.f; }
    if (d >= 3)  { a0 = a1; a1 = a2; a2 = a3; a3 = 0.f; }
    if (d <= -1) { a3 = a2; a2 = a1; a1 = a0; a0 = 0.f; }
    if (d <= -2) { a3 = a2; a2 = a1; a1 = a0; a0 = 0.f; }
    if (d <= -3) { a3 = a2; a2 = a1; a1 = a0; a0 = 0.f; }
    uint4 r;
    if (pbc & 1) {        // window (0,a0,a1,a2,a3,0)
        r.x = pk_bf16x2(0.f, a0);
        r.y = pk_bf16x2(a1, a2);
        r.z = pk_bf16x2(a3, 0.f);
    } else {              // window (a0,a1,a2,a3,0,0)
        r.x = pk_bf16x2(a0, a1);
        r.y = pk_bf16x2(a2, a3);
        r.z = 0u;
    }
    r.w = (unsigned)(pbc & ~1) |
          ((unsigned)__half_as_ushort(__float2half(tx)) << 16);
    return r;
}

__global__ void kan_zero(float* __restrict__ y) {
    y[(size_t)blockIdx.x * 256 + threadIdx.x] = 0.f;
}

__global__ __launch_bounds__(512, 4) void kan_main(
    const float* __restrict__ x, const float* __restrict__ W,
    const float* __restrict__ sw, float* __restrict__ y)
{
    const int bid = blockIdx.x;
    const int bc = bid & 1;             // fastest: b-split sharers co-resident
    const int oc = (bid >> 1) & 15;
    const int ig = bid >> 5;            // [0,32)
    const int o0 = oc * 16, i0 = ig * 16, b0 = bc * 512;
    const int t = threadIdx.x;

    __shared__ __align__(16) unsigned slab[2][SLABW];   // 18.6 KB
    __shared__ __align__(16) uint4 wpk[2][512];         // 16 KB
    __shared__ float Wl[2][16];

    // compute mapping: b = wv*64 + bp*16 + bl; o = o0 + og*4 + j
    const int wv = t >> 6, bl = (t >> 2) & 15, og = t & 3;
    const int og2 = og << 1;
    // staging mapping: o-row soo, g-chunk gc
    const int soo = t >> 5;             // [0,16)
    const int gc  = t & 31;             // [0,32)

    const float* swrow = sw + ((size_t)(o0 + soo) * N_IN + i0) * NCOEF;
    const float* xp    = x + (size_t)(b0 + t) * N_IN + i0;
    const float* wgp   = W + (size_t)(o0 + (t & 15)) * N_IN + i0;

    float4 sA, sB;
    float sT = 0.f, Wc = 0.f, xc, xn;

#define GLOAD(ii) do {                                            \
        const float* _r = swrow + (size_t)(ii) * NCOEF;           \
        sA = *(const float4*)&_r[gc * 4];                         \
        sB = *(const float4*)&_r[gc * 4 + 128];                   \
        if (gc == 0) sT = _r[256];                                \
    } while (0)

#define STAGE(SL) do {                                            \
        const int qa = gc * 2, qb = qa + 64;                      \
        (SL)[SLOT(qa,     soo)] = pk_bf16x2(sA.x, sA.y);          \
        (SL)[SLOT(qa + 1, soo)] = pk_bf16x2(sA.z, sA.w);          \
        (SL)[SLOT(qb,     soo)] = pk_bf16x2(sB.x, sB.y);          \
        (SL)[SLOT(qb + 1, soo)] = pk_bf16x2(sB.z, sB.w);          \
        if (gc == 0) (SL)[128 * ROWQ + soo] = pk_bf16x2(sT, 0.f); \
    } while (0)

    // ---- prologue: stage i=0 into buf0, prefetch i=1
    xc = xp[0];
    GLOAD(0);
    if (t < 16) Wc = wgp[0];
    unsigned* slC = slab[0]; unsigned* slN = slab[1];
    uint4*    wkC = wpk[0];  uint4*    wkN = wpk[1];
    float*    WlC = Wl[0];   float*    WlN = Wl[1];
    STAGE(slC);
    wkC[t] = spline_pack(xc);
    if (t < 16) WlC[t] = Wc;
    xn = xp[1];
    GLOAD(1);
    if (t < 16) Wc = wgp[1];

    float4 acc[4];
#pragma unroll
    for (int bp = 0; bp < 4; ++bp) acc[bp] = make_float4(0.f, 0.f, 0.f, 0.f);

    __syncthreads();

    for (int n = 0; n < 16; ++n) {
        // ---- compute i=n from slC / wkC / WlC
        const float4 Wv = *(const float4*)&WlC[og << 2];
#pragma unroll
        for (int bp = 0; bp < 4; ++bp) {
            const uint4 u = wkC[wv * 64 + (bp << 4) + bl];   // b128 broadcast x4
            const int pe = (int)(u.w & 0xffffu);
            const float tx =
                __half2float(__ushort_as_half((unsigned short)(u.w >> 16)));
            const int q0 = pe >> 1;
            float4 a = acc[bp];
            a.x = fmaf(tx, Wv.x, a.x);
            a.y = fmaf(tx, Wv.y, a.y);
            a.z = fmaf(tx, Wv.z, a.z);
            a.w = fmaf(tx, Wv.w, a.w);
            if (u.x | u.y | u.z) {      // ~69% of lanes: spline support
#pragma unroll
                for (int j = 0; j < 3; ++j) {
                    const int q = q0 + j;
                    const int s = og2 ^ (q & 7);
                    const int rb = q * ROWQ;
                    const uint2 A = *(const uint2*)&slC[rb + (s << 1)];
                    const uint2 B = *(const uint2*)&slC[rb + ((s ^ 1) << 1)];
                    const unsigned wj = (j == 0) ? u.x : (j == 1) ? u.y : u.z;
                    a.x = dot2bf(wj, A.x, a.x);
                    a.y = dot2bf(wj, A.y, a.y);
                    a.z = dot2bf(wj, B.x, a.z);
                    a.w = dot2bf(wj, B.y, a.w);
                }
            }
            acc[bp] = a;
        }

        // ---- stage i=n+1 into the other buffer; prefetch i=n+2
        if (n + 1 < 16) {
            STAGE(slN);
            wkN[t] = spline_pack(xn);
            if (t < 16) WlN[t] = Wc;
            if (n + 2 < 16) {
                xn = xp[n + 2];
                GLOAD(n + 2);
                if (t < 16) Wc = wgp[n + 2];
            }
        }
        __syncthreads();
        { unsigned* z = slC; slC = slN; slN = z; }
        { uint4*    z = wkC; wkC = wkN; wkN = z; }
        { float*    z = WlC; WlC = WlN; WlN = z; }
    }

    // ---- accumulate into y via device atomics (32 i-groups sum here)
    float* yb = y + (size_t)b0 * N_OUT + o0 + (og << 2);
#pragma unroll
    for (int bp = 0; bp < 4; ++bp) {
        const int lb = wv * 64 + (bp << 4) + bl;
        float* p = yb + (size_t)lb * N_OUT;
        atomicAdd(p + 0, acc[bp].x);
        atomicAdd(p + 1, acc[bp].y);
        atomicAdd(p + 2, acc[bp].z);
        atomicAdd(p + 3, acc[bp].w);
    }
#undef GLOAD
#undef STAGE
}

__global__ __launch_bounds__(256) void kan_ln(
    const float* __restrict__ y, const float* __restrict__ prelu_a,
    float* __restrict__ out)
{
    const int b = blockIdx.x;
    const int t = threadIdx.x;

    const float sv = y[(size_t)b * N_OUT + t];

    float v1 = sv, v2 = sv * sv;
#pragma unroll
    for (int d = 1; d < 64; d <<= 1) {
        v1 += __shfl_xor(v1, d);
        v2 += __shfl_xor(v2, d);
    }
    __shared__ float r1[4], r2[4];
    if ((t & 63) == 0) { r1[t >> 6] = v1; r2[t >> 6] = v2; }
    __syncthreads();
    const float tot1 = r1[0] + r1[1] + r1[2] + r1[3];
    const float tot2 = r2[0] + r2[1] + r2[2] + r2[3];

    const float mu  = tot1 * (1.f / N_OUT);
    const float var = tot2 * (1.f / N_OUT) - mu * mu;
    const float inv = rsqrtf(var + LN_EPS);
    const float yn  = (sv - mu) * inv;
    const float a   = prelu_a[0];
    out[(size_t)b * N_OUT + t] = (yn >= 0.f) ? yn : a * yn;
}

extern "C" void kernel_launch(void* const* d_in, const int* in_sizes, int n_in,
                              void* d_out, int out_size, void* d_ws, size_t ws_size,
                              hipStream_t stream)
{
    const float* x  = (const float*)d_in[0];
    const float* W  = (const float*)d_in[1];
    const float* sw = (const float*)d_in[2];
    const float* pa = (const float*)d_in[3];
    float* out = (float*)d_out;
    float* yws = (float*)d_ws;          // BATCH * N_OUT floats = 1 MB

    kan_zero<<<dim3(1024), 256, 0, stream>>>(yws);
    kan_main<<<dim3(1024), 512, 0, stream>>>(x, W, sw, yws);
    kan_ln  <<<dim3(1024), 256, 0, stream>>>(yws, pa, out);
}

// Round 7
// 90.053 us; speedup vs baseline: 1.9015x; 1.8400x over previous
//
#include <hip/hip_runtime.h>
#include <hip/hip_fp16.h>
#include <math.h>

#define N_IN   512
#define N_OUT  256
#define NCOEF  257
#define BATCH  1024
#define LN_EPS 1e-5f
#define G0F (-1.0f - 3.0f * (2.0f / 254.0f))

#define ROWQ 20                 // dwords per q-row: 16 data + 4 pad
#define NQ   129                // q-rows: g-pairs (0,1)..(256,pad)
#define SLABW (NQ * ROWQ)       // 2580 dwords

// physical dword of logical (q-row, o-col oo in [0,16)):
// quad-preserving XOR -> compute reads one aligned b128 per (q, og)
#define SLOT(q_, oo_) ((q_) * ROWQ + (((((oo_) >> 2) ^ ((q_) & 3))) << 2) + ((oo_) & 3))

static __device__ __forceinline__ unsigned pk_bf16x2(float a, float b) {
    unsigned ua = ((__float_as_uint(a) + 0x8000u) >> 16) & 0xffffu;
    unsigned ub = (__float_as_uint(b) + 0x8000u) & 0xffff0000u;
    return ua | ub;
}

static __device__ __forceinline__ float dot2bf(unsigned w, unsigned s, float c) {
    float d;
    asm("v_dot2_f32_bf16 %0, %1, %2, %3" : "=v"(d) : "v"(w), "v"(s), "v"(c));
    return d;
}

// 6-wide even-aligned spline window: w'[j] for g = pe+j, pe = clamp(pb)&~1.
// uint4: x=(w'0,w'1) y=(w'2,w'3) z=(w'4,w'5) bf16-pairs; w = pe | f16(tanh)<<16
static __device__ __forceinline__ uint4 spline_pack(float xv) {
    const float e2 = __expf(2.f * xv);
    const float tx = 1.f - 2.f / (e2 + 1.f);        // tanh(xv)
    const float u  = (xv - G0F) * 127.f;
    const bool has = (u >= 0.f) && (u < 260.f);
    const float uf = has ? u : 0.f;
    int m = (int)uf;
    if (m > 259) m = 259;
    const float tt = uf - (float)m;
    const float t2 = tt * tt, t3 = t2 * tt;
    const float omt = 1.f - tt;
    float a0 = omt * omt * omt * (1.f / 6.f);
    float a1 = (3.f * t3 - 6.f * t2 + 4.f) * (1.f / 6.f);
    float a2 = (-3.f * t3 + 3.f * t2 + 3.f * tt + 1.f) * (1.f / 6.f);
    float a3 = t3 * (1.f / 6.f);
    if (!has) { a0 = a1 = a2 = a3 = 0.f; }
    const int pb  = m - 3;
    const int pbc = pb < 0 ? 0 : (pb > 253 ? 253 : pb);
    const int d   = pbc - pb;                       // [-3,3]
    if (d >= 1)  { a0 = a1; a1 = a2; a2 = a3; a3 = 0.f; }
    if (d >= 2)  { a0 = a1; a1 = a2; a2 = a3; a3 = 0.f; }
    if (d >= 3)  { a0 = a1; a1 = a2; a2 = a3; a3 = 0.f; }
    if (d <= -1) { a3 = a2; a2 = a1; a1 = a0; a0 = 0.f; }
    if (d <= -2) { a3 = a2; a2 = a1; a1 = a0; a0 = 0.f; }
    if (d <= -3) { a3 = a2; a2 = a1; a1 = a0; a0 = 0.f; }
    uint4 r;
    if (pbc & 1) {        // window (0,a0,a1,a2,a3,0)
        r.x = pk_bf16x2(0.f, a0);
        r.y = pk_bf16x2(a1, a2);
        r.z = pk_bf16x2(a3, 0.f);
    } else {              // window (a0,a1,a2,a3,0,0)
        r.x = pk_bf16x2(a0, a1);
        r.y = pk_bf16x2(a2, a3);
        r.z = 0u;
    }
    r.w = (unsigned)(pbc & ~1) |
          ((unsigned)__half_as_ushort(__float2half(tx)) << 16);
    return r;
}

__global__ __launch_bounds__(1024, 4) void kan_main(
    const float* __restrict__ x, const float* __restrict__ W,
    const float* __restrict__ sw, float* __restrict__ part)
{
    const int bid = blockIdx.x;
    const int oc = bid & 15;
    const int ig = bid >> 4;            // [0,16)
    const int o0 = oc * 16, i0 = ig * 32;
    const int t = threadIdx.x;

    __shared__ __align__(16) unsigned slab[2][2][SLABW]; // 41.3 KB
    __shared__ __align__(16) uint4 wpk[2][1024];         // 32 KB (wave-private)
    __shared__ float Wl[2][2][16];

    // compute mapping: b = wv*64 + bp*16 + bl; o = o0 + og*4 + j
    const int wv = t >> 6, l = t & 63;
    const int bl = (l >> 2) & 15, og = l & 3;
    // staging mapping: o-row soo (fast), float4-chunk sgc (slow)
    const int soo = t & 15;             // [0,16)
    const int sgc = t >> 4;             // [0,64): coeffs 4*sgc..4*sgc+3
    // W staging (t<32): sub = t>>4, oo = t&15
    const int wsub = t >> 4;

    const float* swrow = sw + ((size_t)(o0 + soo) * N_IN + i0) * NCOEF;
    const float* xp    = x + (size_t)t * N_IN + i0;
    const float* wgp   = W + (size_t)(o0 + (t & 15)) * N_IN + i0 + wsub;

    float4 pf0, pf1;
    float sT0 = 0.f, sT1 = 0.f, Wc = 0.f;
    float2 xn;

#define GLOAD(p) do {                                             \
        const float* _r0 = swrow + (size_t)(2 * (p)) * NCOEF;     \
        const float* _r1 = _r0 + NCOEF;                           \
        pf0 = *(const float4*)&_r0[sgc * 4];                      \
        pf1 = *(const float4*)&_r1[sgc * 4];                      \
        if (sgc == 63) { sT0 = _r0[256]; sT1 = _r1[256]; }        \
    } while (0)

#define STAGE(wb) do {                                            \
        const int _q = 2 * sgc;                                   \
        unsigned* _s0 = &slab[wb][0][0];                          \
        unsigned* _s1 = &slab[wb][1][0];                          \
        _s0[SLOT(_q,     soo)] = pk_bf16x2(pf0.x, pf0.y);         \
        _s0[SLOT(_q + 1, soo)] = pk_bf16x2(pf0.z, pf0.w);         \
        _s1[SLOT(_q,     soo)] = pk_bf16x2(pf1.x, pf1.y);         \
        _s1[SLOT(_q + 1, soo)] = pk_bf16x2(pf1.z, pf1.w);         \
        if (sgc == 63) {                                          \
            _s0[SLOT(128, soo)] = pk_bf16x2(sT0, 0.f);            \
            _s1[SLOT(128, soo)] = pk_bf16x2(sT1, 0.f);            \
        }                                                         \
    } while (0)

    // ---- prologue: stage pair 0 into buf0; wpk pair 0; prefetch pair 1
    GLOAD(0);
    xn = *(const float2*)&xp[0];
    if (t < 32) Wc = wgp[0];
    STAGE(0);
    if (t < 32) Wl[0][wsub][t & 15] = Wc;
    wpk[0][t] = spline_pack(xn.x);
    wpk[1][t] = spline_pack(xn.y);
    GLOAD(1);
    xn = *(const float2*)&xp[2];
    if (t < 32) Wc = wgp[2];

    float4 acc[4];
#pragma unroll
    for (int bp = 0; bp < 4; ++bp) acc[bp] = make_float4(0.f, 0.f, 0.f, 0.f);

    __syncthreads();

    int buf = 0;
    for (int n = 0; n < 16; ++n) {
        // ---- compute pair n from slab[buf] / wpk / Wl[buf]
#pragma unroll
        for (int sub = 0; sub < 2; ++sub) {
            const float4 Wv = *(const float4*)&Wl[buf][sub][og << 2];
            const unsigned* sl = &slab[buf][sub][0];
#pragma unroll
            for (int bp = 0; bp < 4; ++bp) {
                const uint4 u = wpk[sub][wv * 64 + (bp << 4) + bl];
                const float tx =
                    __half2float(__ushort_as_half((unsigned short)(u.w >> 16)));
                float4 a = acc[bp];
                a.x = fmaf(tx, Wv.x, a.x);
                a.y = fmaf(tx, Wv.y, a.y);
                a.z = fmaf(tx, Wv.z, a.z);
                a.w = fmaf(tx, Wv.w, a.w);
                if (u.x | u.y | u.z) {      // ~69% of lanes have support
                    const int q0 = (int)(u.w & 0xffffu) >> 1;
#pragma unroll
                    for (int j = 0; j < 3; ++j) {
                        const int q = q0 + j;
                        const int ad = q * ROWQ + ((og ^ (q & 3)) << 2);
                        const uint4 s4 = *(const uint4*)&sl[ad];
                        const unsigned wj = (j == 0) ? u.x : (j == 1) ? u.y : u.z;
                        a.x = dot2bf(wj, s4.x, a.x);
                        a.y = dot2bf(wj, s4.y, a.y);
                        a.z = dot2bf(wj, s4.z, a.z);
                        a.w = dot2bf(wj, s4.w, a.w);
                    }
                }
                acc[bp] = a;
            }
        }

        // ---- stage pair n+1; wpk pair n+1 (wave-private: safe after own reads)
        if (n + 1 < 16) {
            STAGE(buf ^ 1);
            if (t < 32) Wl[buf ^ 1][wsub][t & 15] = Wc;
            wpk[0][t] = spline_pack(xn.x);
            wpk[1][t] = spline_pack(xn.y);
            if (n + 2 < 16) {
                GLOAD(n + 2);
                xn = *(const float2*)&xp[2 * (n + 2)];
                if (t < 32) Wc = wgp[2 * (n + 2)];
            }
        }
        __syncthreads();
        buf ^= 1;
    }

    // ---- write partial slab [ig][b][o]
    float* dst = part + ((size_t)ig * BATCH) * N_OUT + o0 + (og << 2);
#pragma unroll
    for (int bp = 0; bp < 4; ++bp) {
        const int lb = wv * 64 + (bp << 4) + bl;
        *reinterpret_cast<float4*>(&dst[(size_t)lb * N_OUT]) = acc[bp];
    }
#undef GLOAD
#undef STAGE
}

__global__ __launch_bounds__(256) void kan_ln(
    const float* __restrict__ part, const float* __restrict__ prelu_a,
    float* __restrict__ out)
{
    const int b = blockIdx.x;
    const int t = threadIdx.x;

    float sv = 0.f;
#pragma unroll
    for (int k = 0; k < 16; ++k)
        sv += part[((size_t)k * BATCH + b) * N_OUT + t];

    float v1 = sv, v2 = sv * sv;
#pragma unroll
    for (int d = 1; d < 64; d <<= 1) {
        v1 += __shfl_xor(v1, d);
        v2 += __shfl_xor(v2, d);
    }
    __shared__ float r1[4], r2[4];
    if ((t & 63) == 0) { r1[t >> 6] = v1; r2[t >> 6] = v2; }
    __syncthreads();
    const float tot1 = r1[0] + r1[1] + r1[2] + r1[3];
    const float tot2 = r2[0] + r2[1] + r2[2] + r2[3];

    const float mu  = tot1 * (1.f / N_OUT);
    const float var = tot2 * (1.f / N_OUT) - mu * mu;
    const float inv = rsqrtf(var + LN_EPS);
    const float yn  = (sv - mu) * inv;
    const float a   = prelu_a[0];
    out[(size_t)b * N_OUT + t] = (yn >= 0.f) ? yn : a * yn;
}

extern "C" void kernel_launch(void* const* d_in, const int* in_sizes, int n_in,
                              void* d_out, int out_size, void* d_ws, size_t ws_size,
                              hipStream_t stream)
{
    const float* x  = (const float*)d_in[0];
    const float* W  = (const float*)d_in[1];
    const float* sw = (const float*)d_in[2];
    const float* pa = (const float*)d_in[3];
    float* out  = (float*)d_out;
    float* part = (float*)d_ws;   // 16 * 1024 * 256 floats = 16 MB

    kan_main<<<dim3(256), 1024, 0, stream>>>(x, W, sw, part);
    kan_ln  <<<dim3(1024), 256, 0, stream>>>(part, pa, out);
}